// Round 7
// baseline (284.028 us; speedup 1.0000x reference)
//
#include <hip/hip_runtime.h>
#include <hip/hip_bf16.h>

// MFBasedModel round 7: mf_route gets async global_load_lds u-staging
// (wave-private LDS double buffer, counted vmcnt(1), zero main-loop barriers,
// XOR-swizzled source so ds_read_b128 is conflict-free). Epilog/cvtC/fallback
// unchanged from the passing round 6.

#define BROWS 16384
#define CNUM  2048
#define KSEL  8
#define DIMD  10
#define MDIM  50
#define TAUI  0.1f
#define UOFF  2432   // word offset of u-staging region in mf_route smem

typedef float    f32x4 __attribute__((ext_vector_type(4)));
typedef _Float16 half8 __attribute__((ext_vector_type(8)));
typedef float    flt2  __attribute__((ext_vector_type(2)));
typedef unsigned int u32;
typedef unsigned long long u64;

__device__ __forceinline__ u32 pkrtz(float a, float b) {
    auto h = __builtin_amdgcn_cvt_pkrtz(a, b);
    union { decltype(h) v; u32 u; } c; c.v = h; return c.u;
}
__device__ __forceinline__ float gnoise(float u) {
    return -__logf(-__logf(u + 1e-20f) + 1e-20f);
}
__device__ __forceinline__ void gload16(const float* g, float* l) {
    __builtin_amdgcn_global_load_lds(
        (const __attribute__((address_space(1))) u32*)g,
        (__attribute__((address_space(3))) u32*)l,
        16, 0, 0);
}

// ---- pre-kernel: C f32 [2048][50] -> fragment-permuted fp16 planes ----
__global__ void cvtC(const float* __restrict__ Cm, u32* __restrict__ C16) {
    const int j = blockIdx.x * 256 + threadIdx.x;   // 131072 words
    const int w = j & 3, l = (j >> 2) & 63, pl = (j >> 8) & 1, Tg = j >> 9;
    const int cand = Tg * 16 + (l & 15);
    const int kk = pl * 16 + ((l >> 4) << 2) + w;
    const int k = 2 * kk;
    const float a = (k < MDIM)     ? Cm[cand*MDIM + k]     : 0.f;
    const float b = (k + 1 < MDIM) ? Cm[cand*MDIM + k + 1] : 0.f;
    C16[j] = pkrtz(a, b);
}

// =================== routing kernel: 8 rows (16 rt) per block ===============
__global__ __launch_bounds__(256, 8)
void mf_route(const int* __restrict__ x32,
              const float* __restrict__ gsrc,
              const float* __restrict__ gtgt,
              const float* __restrict__ suid,
              const float* __restrict__ tuid,
              const float* __restrict__ Cm,
              const float* __restrict__ w1,
              const u32* __restrict__ C16,
              float* __restrict__ gTW,
              int*   __restrict__ gTI)
{
    // words: sPf 832 | T48u 768 | T48l 768 | TS 64 | u-stage 4 waves * 512
    __shared__ __align__(16) float smem[UOFF + 2048];
    __shared__ int sFlag;
    float* sPf  = smem;                  // [16][52]
    u32*   T48u = (u32*)(smem + 832);    // [16][48] smashed
    float* T48l = smem + 1600;           // [16][48] exact l
    float* TS   = smem + 2368;           // [16][4]  exp-sum partials

    const int tid  = threadIdx.x;
    const int row0 = blockIdx.x * 8;

    if (tid == 0) sFlag = 1;
    __syncthreads();
    if (tid < 128) { if (x32[2*tid+1] != 0) atomicAnd(&sFlag, 0); }
    __syncthreads();
    const int is64 = sFlag;

    // sPf = emb @ w1 (f32), 16 row-tasks, zero-padded 52
    for (int t = tid; t < 16*52; t += 256) {
        const int rt = t / 52, mm = t - rt*52;
        float v = 0.f;
        if (mm < MDIM) {
            const int r = row0 + (rt >> 1);
            const int uidx = is64 ? x32[4*r] : x32[2*r];
            const float* tab = (rt & 1) ? suid : tuid;
            #pragma unroll
            for (int d = 0; d < DIMD; ++d) v += tab[uidx*DIMD + d] * w1[d*MDIM + mm];
        }
        sPf[t] = v;
    }
    __syncthreads();

    // wave wv handles cand-quarter wv; lane: lr = rt, lk = k-group
    const int lane = tid & 63, wv = tid >> 6;
    const int lr = lane & 15, lk = lane >> 4;
    const int rt = lr;

    half8 b0, b1;
    {
        union { u32 u[4]; half8 v; } c0, c1;
        #pragma unroll
        for (int jj = 0; jj < 4; ++jj) {
            const int k0 = lk*8 + jj*2;
            c0.u[jj] = pkrtz(sPf[rt*52 + k0], sPf[rt*52 + k0 + 1]);
            const int k1 = 32 + lk*8 + jj*2;
            const float e0 = (k1     < 52) ? sPf[rt*52 + k1]     : 0.f;
            const float e1 = (k1 + 1 < 52) ? sPf[rt*52 + k1 + 1] : 0.f;
            c1.u[jj] = pkrtz(e0, e1);
        }
        b0 = c0.v; b1 = c1.v;
    }

    // ---- u staging geometry ----
    // stage: lane covers LDS words [4*lane, 4*lane+4) of the chunk buffer:
    //   srt = lane>>2 (row-task), phys c4 = lane&3, logical c4 = phys ^ ((srt>>1)&3)
    // read: lane (lr,lk) wants logical c4=lk of rt=lr at phys = lk ^ ((lr>>1)&3)
    const int srt = lane >> 2;
    const int sc4 = (lane & 3) ^ ((srt >> 1) & 3);
    const float* sup = ((srt & 1) ? gsrc : gtgt)
                     + (size_t)(row0 + (srt >> 1)) * CNUM + wv*512 + sc4*4;
    float* const ubase = smem + UOFF + wv*512;                 // wave-uniform
    const int rdoff = UOFF + wv*512 + lr*16 + ((lk ^ ((lr >> 1) & 3)) << 2);

    float ts = 0.f;
    float q0=-3.4e38f,q1=-3.4e38f,q2=-3.4e38f,q3=-3.4e38f,
          q4=-3.4e38f,q5=-3.4e38f,q6=-3.4e38f,q7=-3.4e38f;

    gload16(sup, ubase);                                       // stage chunk 0

    for (int t = 0; t < 32; ++t) {
        if (t + 1 < 32) {
            gload16(sup + (t + 1)*16, ubase + ((t + 1) & 1)*256);
            asm volatile("s_waitcnt vmcnt(1)" ::: "memory");   // chunk t ready
        } else {
            asm volatile("s_waitcnt vmcnt(0)" ::: "memory");
        }
        const f32x4 u4 = *(const f32x4*)&smem[rdoff + (t & 1)*256];
        const int cb = wv*512 + t*16;
        const u32* cp = C16 + (size_t)((wv*32 + t)*128 + lane)*4;
        const half8 a0 = *(const half8*)cp;
        const half8 a1 = *(const half8*)(cp + 256);
        f32x4 acc = {0.f, 0.f, 0.f, 0.f};
        acc = __builtin_amdgcn_mfma_f32_16x16x32_f16(a0, b0, acc, 0, 0, 0);
        acc = __builtin_amdgcn_mfma_f32_16x16x32_f16(a1, b1, acc, 0, 0, 0);
        const int cg = cb + lk*4;
        #pragma unroll
        for (int r4 = 0; r4 < 4; ++r4) {
            const float l = (acc[r4] + gnoise(u4[r4])) * TAUI;
            ts += __expf(l);
            const float xs = __uint_as_float(
                (__float_as_uint(l) & 0xFFFFF800u) | (u32)(cg + r4));
            q0 = fmaxf(q0, fminf(q1, xs));
            q1 = fmaxf(q1, fminf(q2, xs));
            q2 = fmaxf(q2, fminf(q3, xs));
            q3 = fmaxf(q3, fminf(q4, xs));
            q4 = fmaxf(q4, fminf(q5, xs));
            q5 = fmaxf(q5, fminf(q6, xs));
            q6 = fmaxf(q6, fminf(q7, xs));
            q7 = fmaxf(q7, xs);
        }
    }

    // merge over lk lanes: exp-sum + top-12 tournament per (rt, quarter)
    {
        float tss = ts;
        tss += __shfl_xor(tss, 16); tss += __shfl_xor(tss, 32);
        if (lk == 0) TS[rt*4 + wv] = tss;
        #pragma unroll
        for (int k = 0; k < 12; ++k) {
            float gm = fmaxf(q7, __shfl_xor(q7, 16));
            gm = fmaxf(gm, __shfl_xor(gm, 32));
            if (q7 == gm) {
                T48u[rt*48 + wv*12 + k] = __float_as_uint(q7);
                q7=q6; q6=q5; q5=q4; q4=q3; q3=q2; q2=q1; q1=q0; q0=-3.4e38f;
            }
        }
    }
    __syncthreads();

    // exact f32 recompute of the 48 candidates per rt
    for (int e = tid; e < 16*48; e += 256) {
        const int ert = e / 48;
        const int idx = (int)(T48u[e] & 2047u);
        const float* pf = sPf + ert*52;
        const float* cr = Cm + idx*MDIM;
        float s = 0.f;
        #pragma unroll
        for (int k2 = 0; k2 < 25; ++k2) {
            flt2 c = *(const flt2*)(cr + k2*2);
            s += pf[2*k2] * c.x + pf[2*k2+1] * c.y;
        }
        const int r = row0 + (ert >> 1);
        const float u = ((ert & 1) ? gsrc : gtgt)[(size_t)r*CNUM + idx];
        T48l[e] = (s + gnoise(u)) * TAUI;
    }
    __syncthreads();

    // finalize: exact top-8 of 48 (tiebreak lower index) -> global
    if (tid < 16) {
        const int r8 = tid;
        const float inv = 1.0f / (TS[r8*4] + TS[r8*4+1] + TS[r8*4+2] + TS[r8*4+3]);
        u64 used = 0;
        for (int k = 0; k < KSEL; ++k) {
            float bl = -3.4e38f; int bi = 1 << 30; int bj = 0;
            for (int j = 0; j < 48; ++j) {
                if ((used >> j) & 1ull) continue;
                const float lv = T48l[r8*48 + j];
                const int   iv = (int)(T48u[r8*48 + j] & 2047u);
                if (lv > bl || (lv == bl && iv < bi)) { bl = lv; bi = iv; bj = j; }
            }
            used |= 1ull << bj;
            const int grt = blockIdx.x*16 + r8;
            gTW[grt*KSEL + k] = __expf(bl) * inv;
            gTI[grt*KSEL + k] = bi;
        }
    }
}

// =================== epilogue kernel: 16 rows per block =====================
__global__ __launch_bounds__(256, 4)
void mf_epilog(const int* __restrict__ x32,
               const float* __restrict__ suid,
               const float* __restrict__ tiid,
               const float* __restrict__ Cm,
               const float* __restrict__ w2,
               const float* __restrict__ mw1,
               const float* __restrict__ mb1,
               const float* __restrict__ mw2,
               const float* __restrict__ mb2,
               const float* __restrict__ gTW,
               const int*   __restrict__ gTI,
               float* __restrict__ out)
{
    __shared__ int sFlag;
    const int tid = threadIdx.x;
    const int g = tid >> 4, lg = tid & 15;
    const int row = blockIdx.x * 16 + g;

    if (tid == 0) sFlag = 1;
    __syncthreads();
    if (tid < 128) { if (x32[2*tid+1] != 0) atomicAnd(&sFlag, 0); }
    __syncthreads();
    const int is64 = sFlag;

    const int uidx = is64 ? x32[4*row]     : x32[2*row];
    const int iidx = is64 ? x32[4*row + 2] : x32[2*row + 1];

    float uid[10], ti[10];
    #pragma unroll
    for (int d = 0; d < DIMD; ++d) uid[d] = suid[(size_t)uidx*DIMD + d];
    #pragma unroll
    for (int e = 0; e < DIMD; ++e) ti[e] = tiid[(size_t)iidx*DIMD + e];

    float twt[8], tws[8]; int it[8], is_[8];
    #pragma unroll
    for (int k = 0; k < KSEL; ++k) {
        twt[k] = gTW[(row*2)*KSEL + k];     it[k]  = gTI[(row*2)*KSEL + k];
        tws[k] = gTW[(row*2+1)*KSEL + k];   is_[k] = gTI[(row*2+1)*KSEL + k];
    }

    const int j0 = 4*lg;
    const int nj = (j0 + 4 <= MDIM) ? 4 : (j0 < MDIM ? MDIM - j0 : 0);

    float po = 0.f;
    float qt[4] = {0,0,0,0}, w2t[4] = {0,0,0,0}, hb[4] = {0,0,0,0};

    if (nj) {
        {
            flt2 m0 = *(const flt2*)(mb1 + j0);
            hb[0] = m0.x; hb[1] = m0.y;
            if (nj == 4) { flt2 m1 = *(const flt2*)(mb1 + j0 + 2); hb[2] = m1.x; hb[3] = m1.y; }
            #pragma unroll
            for (int d = 0; d < DIMD; ++d) {
                const float* r = mw1 + (MDIM + d)*MDIM + j0;
                flt2 a = *(const flt2*)r;
                hb[0] += uid[d]*a.x; hb[1] += uid[d]*a.y;
                if (nj == 4) { flt2 b = *(const flt2*)(r + 2); hb[2] += uid[d]*b.x; hb[3] += uid[d]*b.y; }
            }
        }
        for (int jj = 0; jj < nj; ++jj) {
            const float* r = w2 + (j0 + jj)*DIMD;
            float s = 0.f;
            #pragma unroll
            for (int p = 0; p < 5; ++p) { flt2 a = *(const flt2*)(r + 2*p); s += a.x*ti[2*p] + a.y*ti[2*p+1]; }
            w2t[jj] = s;
        }
        for (int jj = 0; jj < nj; ++jj) {
            const float* r = mw2 + (size_t)(j0 + jj)*(DIMD*DIMD);
            float s = 0.f;
            #pragma unroll
            for (int d = 0; d < DIMD; ++d) {
                float sd = 0.f;
                #pragma unroll
                for (int p = 0; p < 5; ++p) { flt2 a = *(const flt2*)(r + d*DIMD + 2*p); sd += a.x*ti[2*p] + a.y*ti[2*p+1]; }
                s += uid[d]*sd;
            }
            qt[jj] = s;
        }
        {
            float ws[4] = {0,0,0,0};
            #pragma unroll
            for (int k = 0; k < KSEL; ++k) {
                const float* cr = Cm + (size_t)it[k]*MDIM + j0;
                flt2 a = *(const flt2*)cr;
                ws[0] += twt[k]*a.x; ws[1] += twt[k]*a.y;
                if (nj == 4) { flt2 b = *(const flt2*)(cr + 2); ws[2] += twt[k]*b.x; ws[3] += twt[k]*b.y; }
            }
            for (int jj = 0; jj < nj; ++jj) po += ws[jj]*w2t[jj];
        }
        float hk[8][4];
        #pragma unroll
        for (int k = 0; k < KSEL; ++k)
            #pragma unroll
            for (int jj = 0; jj < 4; ++jj) hk[k][jj] = hb[jj];
        for (int t2 = 0; t2 < MDIM; t2 += 2) {
            const float* r0 = mw1 + t2*MDIM + j0;
            const float* r1 = mw1 + (t2+1)*MDIM + j0;
            flt2 wa0 = *(const flt2*)r0, wb0 = *(const flt2*)(r0 + 2);
            flt2 wa1 = *(const flt2*)r1, wb1 = *(const flt2*)(r1 + 2);
            #pragma unroll
            for (int k = 0; k < KSEL; ++k) {
                flt2 c = *(const flt2*)(Cm + (size_t)is_[k]*MDIM + t2);
                hk[k][0] += c.x*wa0.x + c.y*wa1.x;
                hk[k][1] += c.x*wa0.y + c.y*wa1.y;
                hk[k][2] += c.x*wb0.x + c.y*wb1.x;
                hk[k][3] += c.x*wb0.y + c.y*wb1.y;
            }
        }
        #pragma unroll
        for (int k = 0; k < KSEL; ++k) {
            float s = 0.f;
            for (int jj = 0; jj < nj; ++jj) s += fmaxf(hk[k][jj], 0.f)*qt[jj];
            po += tws[k]*s;
        }
    }
    if (lg == 0) {
        float stw = 0.f;
        #pragma unroll
        for (int k = 0; k < KSEL; ++k) stw += tws[k];
        float bt = 0.f;
        #pragma unroll
        for (int d = 0; d < DIMD; ++d) {
            float sd = 0.f;
            #pragma unroll
            for (int e = 0; e < DIMD; ++e) sd += mb2[d*DIMD + e]*ti[e];
            bt += uid[d]*sd;
        }
        po += stw*bt;
    }
    po += __shfl_xor(po, 1, 16);
    po += __shfl_xor(po, 2, 16);
    po += __shfl_xor(po, 4, 16);
    po += __shfl_xor(po, 8, 16);
    if (lg == 0) out[row] = po;
}

// =================== fused fallback (validated, non-PRE path) ===============
__global__ __launch_bounds__(256, 4)
void mf_fused_fb(const int* __restrict__ x32,
                 const float* __restrict__ gsrc,
                 const float* __restrict__ gtgt,
                 const float* __restrict__ suid,
                 const float* __restrict__ tuid,
                 const float* __restrict__ tiid,
                 const float* __restrict__ Cm,
                 const float* __restrict__ w1,
                 const float* __restrict__ w2,
                 const float* __restrict__ mw1,
                 const float* __restrict__ mb1,
                 const float* __restrict__ mw2,
                 const float* __restrict__ mb2,
                 float* __restrict__ out)
{
    __shared__ __align__(16) float smem[9536];
    __shared__ int sFlag;
    float* sPf  = smem;
    u32*   T24u = (u32*)(smem + 1664);
    float* T24l = smem + 2432;

    const int tid  = threadIdx.x;
    const int row0 = blockIdx.x * 16;

    if (tid == 0) sFlag = 1;
    __syncthreads();
    if (tid < 128) { if (x32[2*tid+1] != 0) atomicAnd(&sFlag, 0); }
    __syncthreads();
    const int is64 = sFlag;

    for (int t = tid; t < 32*52; t += 256) {
        const int rt = t / 52, mm = t - rt*52;
        float v = 0.f;
        if (mm < MDIM) {
            const int r = row0 + (rt >> 1);
            const int uidx = is64 ? x32[4*r] : x32[2*r];
            const float* tab = (rt & 1) ? suid : tuid;
            #pragma unroll
            for (int d = 0; d < DIMD; ++d) v += tab[uidx*DIMD + d] * w1[d*MDIM + mm];
        }
        sPf[t] = v;
    }
    __syncthreads();

    const int lane = tid & 63, wv = tid >> 6;
    const int lr = lane & 15, lk = lane >> 4;
    const int g = wv & 1, h = wv >> 1;
    const int rt = g*16 + lr;
    const float* up = ((lr & 1) ? gsrc : gtgt) + (size_t)(row0 + g*8 + (lr >> 1)) * CNUM;

    half8 b0, b1;
    {
        union { u32 u[4]; half8 v; } c0, c1;
        #pragma unroll
        for (int jj = 0; jj < 4; ++jj) {
            const int k0 = lk*8 + jj*2;
            c0.u[jj] = pkrtz(sPf[rt*52 + k0], sPf[rt*52 + k0 + 1]);
            const int k1 = 32 + lk*8 + jj*2;
            const float e0 = (k1     < 52) ? sPf[rt*52 + k1]     : 0.f;
            const float e1 = (k1 + 1 < 52) ? sPf[rt*52 + k1 + 1] : 0.f;
            c1.u[jj] = pkrtz(e0, e1);
        }
        b0 = c0.v; b1 = c1.v;
    }

    float ts = 0.f;
    float q0=-3.4e38f,q1=-3.4e38f,q2=-3.4e38f,q3=-3.4e38f,
          q4=-3.4e38f,q5=-3.4e38f,q6=-3.4e38f,q7=-3.4e38f;

    for (int t = 0; t < 64; ++t) {
        const int cb = ((t >> 2) << 7) + h*64 + ((t & 3) << 4);
        const float* cr = Cm + (size_t)(cb + lr)*MDIM;
        union { u32 u[4]; half8 v; } c0, c1;
        #pragma unroll
        for (int jj = 0; jj < 4; ++jj) {
            const int k0 = lk*8 + jj*2;
            c0.u[jj] = pkrtz(cr[k0], cr[k0+1]);
            const int k1 = 32 + lk*8 + jj*2;
            const float e0 = (k1     < MDIM) ? cr[k1]   : 0.f;
            const float e1 = (k1 + 1 < MDIM) ? cr[k1+1] : 0.f;
            c1.u[jj] = pkrtz(e0, e1);
        }
        f32x4 acc = {0.f, 0.f, 0.f, 0.f};
        acc = __builtin_amdgcn_mfma_f32_16x16x32_f16(c0.v, b0, acc, 0, 0, 0);
        acc = __builtin_amdgcn_mfma_f32_16x16x32_f16(c1.v, b1, acc, 0, 0, 0);
        const f32x4 u4 = *(const f32x4*)(up + cb + lk*4);
        const int cg = cb + lk*4;
        #pragma unroll
        for (int r4 = 0; r4 < 4; ++r4) {
            const float l = (acc[r4] + gnoise(u4[r4])) * TAUI;
            ts += __expf(l);
            const float xs = __uint_as_float(
                (__float_as_uint(l) & 0xFFFFF800u) | (u32)(cg + r4));
            q0 = fmaxf(q0, fminf(q1, xs));
            q1 = fmaxf(q1, fminf(q2, xs));
            q2 = fmaxf(q2, fminf(q3, xs));
            q3 = fmaxf(q3, fminf(q4, xs));
            q4 = fmaxf(q4, fminf(q5, xs));
            q5 = fmaxf(q5, fminf(q6, xs));
            q6 = fmaxf(q6, fminf(q7, xs));
            q7 = fmaxf(q7, xs);
        }
    }

    {
        float tss = ts;
        tss += __shfl_xor(tss, 16); tss += __shfl_xor(tss, 32);
        if (lk == 0) smem[3200 + rt*2 + h] = tss;
        #pragma unroll
        for (int k = 0; k < 12; ++k) {
            float gm = fmaxf(q7, __shfl_xor(q7, 16));
            gm = fmaxf(gm, __shfl_xor(gm, 32));
            if (q7 == gm) {
                T24u[rt*24 + h*12 + k] = __float_as_uint(q7);
                q7=q6; q6=q5; q5=q4; q4=q3; q3=q2; q2=q1; q1=q0; q0=-3.4e38f;
            }
        }
    }
    __syncthreads();

    for (int e = tid; e < 32*24; e += 256) {
        const int ert = e / 24;
        const int idx = (int)(T24u[e] & 2047u);
        const float* pf = sPf + ert*52;
        const float* cr = Cm + idx*MDIM;
        float s = 0.f;
        #pragma unroll
        for (int k2 = 0; k2 < 25; ++k2) {
            flt2 c = *(const flt2*)(cr + k2*2);
            s += pf[2*k2] * c.x + pf[2*k2+1] * c.y;
        }
        const int r = row0 + (ert >> 1);
        const float u = ((ert & 1) ? gsrc : gtgt)[(size_t)r*CNUM + idx];
        T24l[e] = (s + gnoise(u)) * TAUI;
    }
    __syncthreads();

    if (tid < 32) {
        const int rrt = tid;
        const float inv = 1.0f / (smem[3200 + rrt*2] + smem[3200 + rrt*2 + 1]);
        u32 used = 0;
        for (int k = 0; k < KSEL; ++k) {
            float bl = -3.4e38f; int bi = 1 << 30; int bj = 0;
            for (int j = 0; j < 24; ++j) {
                if ((used >> j) & 1) continue;
                const float lv = T24l[rrt*24 + j];
                const int   iv = (int)(T24u[rrt*24 + j] & 2047u);
                if (lv > bl || (lv == bl && iv < bi)) { bl = lv; bi = iv; bj = j; }
            }
            used |= 1u << bj;
            smem[8832 + rrt*KSEL + k] = __expf(bl) * inv;
            ((int*)smem)[9088 + rrt*KSEL + k] = bi;
        }
    }
    __syncthreads();

    float* sH    = smem;
    float* sQ    = smem + 832;
    float* sUd   = smem + 9344;
    float* sTopW = smem + 8832;
    int*   sTopI = (int*)smem + 9088;

    const int gg = tid >> 4, lg = tid & 15;
    const int row = row0 + gg;
    const int rt_t = gg*2, rt_s = gg*2 + 1;
    const int uidx = is64 ? x32[4*row]     : x32[2*row];
    const int iidx = is64 ? x32[4*row + 2] : x32[2*row + 1];

    if (lg < DIMD) sUd[gg*12 + lg] = suid[uidx*DIMD + lg];
    __syncthreads();

    for (int t = lg; t < MDIM*DIMD; t += 16) {
        const int j = t / DIMD, e = t - j*DIMD;
        float q = 0.f;
        #pragma unroll
        for (int d = 0; d < DIMD; ++d) q += sUd[gg*12 + d] * mw2[j*(DIMD*DIMD) + d*DIMD + e];
        sQ[gg*500 + t] = q;
    }
    for (int mm = lg; mm < MDIM; mm += 16) {
        float v = 0.f;
        #pragma unroll
        for (int k = 0; k < KSEL; ++k)
            v += sTopW[rt_t*KSEL + k] * Cm[sTopI[rt_t*KSEL + k]*MDIM + mm];
        sH[gg*52 + mm] = v;
    }
    __syncthreads();

    float acc_e = 0.f, be = 0.f;
    if (lg < DIMD) {
        for (int m2 = 0; m2 < MDIM; ++m2) acc_e += sH[gg*52 + m2] * w2[m2*DIMD + lg];
        #pragma unroll
        for (int d = 0; d < DIMD; ++d) be += sUd[gg*12 + d] * mb2[d*DIMD + lg];
    }
    __syncthreads();

    for (int k = 0; k < KSEL; ++k) {
        const int   ik = sTopI[rt_s*KSEL + k];
        const float tw = sTopW[rt_s*KSEL + k];
        for (int j = lg; j < MDIM; j += 16) {
            float hh = mb1[j];
            const float* crow = Cm + ik*MDIM;
            for (int t2 = 0; t2 < MDIM; ++t2) hh += crow[t2] * mw1[t2*MDIM + j];
            #pragma unroll
            for (int d = 0; d < DIMD; ++d) hh += sUd[gg*12 + d] * mw1[(MDIM + d)*MDIM + j];
            sH[gg*52 + j] = fmaxf(hh, 0.f);
        }
        __syncthreads();
        if (lg < DIMD) {
            float se = be;
            for (int j = 0; j < MDIM; ++j) se += sH[gg*52 + j] * sQ[gg*500 + j*DIMD + lg];
            acc_e += tw * se;
        }
        __syncthreads();
    }

    float o = 0.f;
    if (lg < DIMD) o = acc_e * tiid[iidx*DIMD + lg];
    #pragma unroll
    for (int k = 8; k >= 1; k >>= 1) o += __shfl_xor(o, k, 16);
    if (lg == 0) out[row] = o;
}

extern "C" void kernel_launch(void* const* d_in, const int* in_sizes, int n_in,
                              void* d_out, int out_size, void* d_ws, size_t ws_size,
                              hipStream_t stream) {
    (void)in_sizes; (void)n_in; (void)out_size;
    const int*   x32  = (const int*)d_in[0];
    const float* gsrc = (const float*)d_in[1];
    const float* gtgt = (const float*)d_in[2];
    const float* suid = (const float*)d_in[3];
    const float* tuid = (const float*)d_in[4];
    const float* tiid = (const float*)d_in[5];
    const float* Cm   = (const float*)d_in[6];
    const float* w1   = (const float*)d_in[7];
    const float* w2   = (const float*)d_in[8];
    const float* mw1  = (const float*)d_in[9];
    const float* mb1  = (const float*)d_in[10];
    const float* mw2  = (const float*)d_in[11];
    const float* mb2  = (const float*)d_in[12];

    // ws layout (words): C16 [0,131072) ; gTW [131072,393216) ; gTI [393216,655360)
    if (ws_size >= 655360u * 4u) {
        u32*   C16 = (u32*)d_ws;
        float* gTW = (float*)d_ws + 131072;
        int*   gTI = (int*)d_ws + 393216;
        hipLaunchKernelGGL(cvtC, dim3(512), dim3(256), 0, stream, Cm, C16);
        hipLaunchKernelGGL(mf_route, dim3(BROWS/8), dim3(256), 0, stream,
                           x32, gsrc, gtgt, suid, tuid, Cm, w1, C16, gTW, gTI);
        hipLaunchKernelGGL(mf_epilog, dim3(BROWS/16), dim3(256), 0, stream,
                           x32, suid, tiid, Cm, w2, mw1, mb1, mw2, mb2, gTW, gTI,
                           (float*)d_out);
    } else {
        hipLaunchKernelGGL(mf_fused_fb, dim3(BROWS/16), dim3(256), 0, stream,
                           x32, gsrc, gtgt, suid, tuid, tiid, Cm, w1, w2, mw1, mb1, mw2, mb2,
                           (float*)d_out);
    }
}

// Round 8
// 278.059 us; speedup vs baseline: 1.0215x; 1.0215x over previous
//
#include <hip/hip_runtime.h>
#include <hip/hip_bf16.h>

// MFBasedModel round 8: u-stream restructured for DRAM locality. Block-level
// 128-cand chunks staged via global_load_lds where each instruction reads
// 2 rows x 512 B CONTIGUOUS (vs 16 rows x 64 B before). Double-buffered,
// one __syncthreads per chunk (drain covered by compute). Waves split cands
// by tile-within-chunk. Everything downstream identical to passing round 7.

#define BROWS 16384
#define CNUM  2048
#define KSEL  8
#define DIMD  10
#define MDIM  50
#define TAUI  0.1f
#define UOFF  832    // word offset of u staging region (2 bufs x 2048 words)

typedef float    f32x4 __attribute__((ext_vector_type(4)));
typedef _Float16 half8 __attribute__((ext_vector_type(8)));
typedef float    flt2  __attribute__((ext_vector_type(2)));
typedef unsigned int u32;
typedef unsigned long long u64;

__device__ __forceinline__ u32 pkrtz(float a, float b) {
    auto h = __builtin_amdgcn_cvt_pkrtz(a, b);
    union { decltype(h) v; u32 u; } c; c.v = h; return c.u;
}
__device__ __forceinline__ float gnoise(float u) {
    return -__logf(-__logf(u + 1e-20f) + 1e-20f);
}
__device__ __forceinline__ void gload16(const float* g, float* l) {
    __builtin_amdgcn_global_load_lds(
        (const __attribute__((address_space(1))) u32*)g,
        (__attribute__((address_space(3))) u32*)l,
        16, 0, 0);
}

// ---- pre-kernel: C f32 [2048][50] -> fragment-permuted fp16 planes ----
__global__ void cvtC(const float* __restrict__ Cm, u32* __restrict__ C16) {
    const int j = blockIdx.x * 256 + threadIdx.x;   // 131072 words
    const int w = j & 3, l = (j >> 2) & 63, pl = (j >> 8) & 1, Tg = j >> 9;
    const int cand = Tg * 16 + (l & 15);
    const int kk = pl * 16 + ((l >> 4) << 2) + w;
    const int k = 2 * kk;
    const float a = (k < MDIM)     ? Cm[cand*MDIM + k]     : 0.f;
    const float b = (k + 1 < MDIM) ? Cm[cand*MDIM + k + 1] : 0.f;
    C16[j] = pkrtz(a, b);
}

// =================== routing kernel: 8 rows (16 rt) per block ===============
__global__ __launch_bounds__(256, 8)
void mf_route(const int* __restrict__ x32,
              const float* __restrict__ gsrc,
              const float* __restrict__ gtgt,
              const float* __restrict__ suid,
              const float* __restrict__ tuid,
              const float* __restrict__ Cm,
              const float* __restrict__ w1,
              const u32* __restrict__ C16,
              float* __restrict__ gTW,
              int*   __restrict__ gTI)
{
    // words: sPf [0,832) | U dbuf [832, 832+4096)
    // post-loop overlay in U: T48u @832 (768), T48l @1600 (768), TS @2368 (64)
    __shared__ __align__(16) float smem[UOFF + 4096];
    __shared__ int sFlag;
    float* sPf  = smem;                  // [16][52]
    u32*   T48u = (u32*)(smem + 832);
    float* T48l = smem + 1600;
    float* TS   = smem + 2368;

    const int tid  = threadIdx.x;
    const int row0 = blockIdx.x * 8;

    if (tid == 0) sFlag = 1;
    __syncthreads();
    if (tid < 128) { if (x32[2*tid+1] != 0) atomicAnd(&sFlag, 0); }
    __syncthreads();
    const int is64 = sFlag;

    // sPf = emb @ w1 (f32), 16 row-tasks, zero-padded 52
    for (int t = tid; t < 16*52; t += 256) {
        const int rt = t / 52, mm = t - rt*52;
        float v = 0.f;
        if (mm < MDIM) {
            const int r = row0 + (rt >> 1);
            const int uidx = is64 ? x32[4*r] : x32[2*r];
            const float* tab = (rt & 1) ? suid : tuid;
            #pragma unroll
            for (int d = 0; d < DIMD; ++d) v += tab[uidx*DIMD + d] * w1[d*MDIM + mm];
        }
        sPf[t] = v;
    }
    __syncthreads();

    const int lane = tid & 63, w = tid >> 6;
    const int lr = lane & 15, lk = lane >> 4;
    const int rt = lr;

    // B-fragments: P16[rt][k] from sPf
    half8 b0, b1;
    {
        union { u32 u[4]; half8 v; } c0, c1;
        #pragma unroll
        for (int jj = 0; jj < 4; ++jj) {
            const int k0 = lk*8 + jj*2;
            c0.u[jj] = pkrtz(sPf[rt*52 + k0], sPf[rt*52 + k0 + 1]);
            const int k1 = 32 + lk*8 + jj*2;
            const float e0 = (k1     < 52) ? sPf[rt*52 + k1]     : 0.f;
            const float e1 = (k1 + 1 < 52) ? sPf[rt*52 + k1 + 1] : 0.f;
            c1.u[jj] = pkrtz(e0, e1);
        }
        b0 = c0.v; b1 = c1.v;
    }

    // ---- u staging: 128-cand chunks, 2 instrs/wave, 2 rows x 512B each ----
    const int jrow = lane >> 5, jc4 = lane & 31;
    const int rtS0 = 4*w + jrow;            // instr0 covers rows 4w, 4w+1
    const int rtS1 = 4*w + 2 + jrow;        // instr1 covers rows 4w+2, 4w+3
    const float* usrc0 = ((rtS0 & 1) ? gsrc : gtgt)
        + (size_t)(row0 + (rtS0 >> 1))*CNUM + ((jc4 ^ (rtS0 & 7)) << 2);
    const float* usrc1 = ((rtS1 & 1) ? gsrc : gtgt)
        + (size_t)(row0 + (rtS1 >> 1))*CNUM + ((jc4 ^ (rtS1 & 7)) << 2);
    float* const udst0a = smem + UOFF +        (4*w    )*128;  // buf0, uniform
    float* const udst1a = smem + UOFF +        (4*w + 2)*128;
    float* const udst0b = smem + UOFF + 2048 + (4*w    )*128;  // buf1
    float* const udst1b = smem + UOFF + 2048 + (4*w + 2)*128;

    float ts = 0.f;
    float q0=-3.4e38f,q1=-3.4e38f,q2=-3.4e38f,q3=-3.4e38f,
          q4=-3.4e38f,q5=-3.4e38f,q6=-3.4e38f,q7=-3.4e38f;

    // read addresses (word idx) for this lane's two tiles within any chunk
    const int physa = ((w*8)     + lk) ^ (lr & 7);
    const int physb = ((w*8 + 4) + lk) ^ (lr & 7);
    const int rbase = UOFF + lr*128;

    // prologue: stage chunk 0 into buf0; publish
    gload16(usrc0, udst0a);
    gload16(usrc1, udst1a);
    __syncthreads();

    for (int t = 0; t < 16; ++t) {
        const int bufw = (t & 1) * 2048;
        // 1. read this chunk's u values first (only waits already-landed loads)
        const f32x4 u4a = *(const f32x4*)&smem[rbase + bufw + physa*4];
        const f32x4 u4b = *(const f32x4*)&smem[rbase + bufw + physb*4];
        // 2. issue next chunk's staging (overlaps the compute below)
        if (t + 1 < 16) {
            const int nb = ((t + 1) & 1) * 2048;
            gload16(usrc0 + (t + 1)*128, (nb ? udst0b : udst0a));
            gload16(usrc1 + (t + 1)*128, (nb ? udst1b : udst1a));
        }
        // 3. compute two 16-cand tiles: cl = w*32 + nt*16
        #pragma unroll
        for (int nt = 0; nt < 2; ++nt) {
            const int cl = w*32 + nt*16;
            const int Tg = t*8 + w*2 + nt;
            const u32* cp = C16 + (size_t)(Tg*128 + lane)*4;
            const half8 a0 = *(const half8*)cp;
            const half8 a1 = *(const half8*)(cp + 256);
            f32x4 acc = {0.f, 0.f, 0.f, 0.f};
            acc = __builtin_amdgcn_mfma_f32_16x16x32_f16(a0, b0, acc, 0, 0, 0);
            acc = __builtin_amdgcn_mfma_f32_16x16x32_f16(a1, b1, acc, 0, 0, 0);
            const f32x4 u4 = nt ? u4b : u4a;
            const int cg = t*128 + cl + lk*4;
            #pragma unroll
            for (int r4 = 0; r4 < 4; ++r4) {
                const float l = (acc[r4] + gnoise(u4[r4])) * TAUI;
                ts += __expf(l);
                const float xs = __uint_as_float(
                    (__float_as_uint(l) & 0xFFFFF800u) | (u32)(cg + r4));
                q0 = fmaxf(q0, fminf(q1, xs));
                q1 = fmaxf(q1, fminf(q2, xs));
                q2 = fmaxf(q2, fminf(q3, xs));
                q3 = fmaxf(q3, fminf(q4, xs));
                q4 = fmaxf(q4, fminf(q5, xs));
                q5 = fmaxf(q5, fminf(q6, xs));
                q6 = fmaxf(q6, fminf(q7, xs));
                q7 = fmaxf(q7, xs);
            }
        }
        // 4. publish next chunk (vmcnt(0)+barrier; loads had full compute to land)
        __syncthreads();
    }

    // merge over lk lanes: exp-sum + top-12 tournament per (rt, wave-quarter)
    {
        float tss = ts;
        tss += __shfl_xor(tss, 16); tss += __shfl_xor(tss, 32);
        if (lk == 0) TS[rt*4 + w] = tss;
        #pragma unroll
        for (int k = 0; k < 12; ++k) {
            float gm = fmaxf(q7, __shfl_xor(q7, 16));
            gm = fmaxf(gm, __shfl_xor(gm, 32));
            if (q7 == gm) {
                T48u[rt*48 + w*12 + k] = __float_as_uint(q7);
                q7=q6; q6=q5; q5=q4; q4=q3; q3=q2; q2=q1; q1=q0; q0=-3.4e38f;
            }
        }
    }
    __syncthreads();

    // exact f32 recompute of the 48 candidates per rt
    for (int e = tid; e < 16*48; e += 256) {
        const int ert = e / 48;
        const int idx = (int)(T48u[e] & 2047u);
        const float* pf = sPf + ert*52;
        const float* cr = Cm + idx*MDIM;
        float s = 0.f;
        #pragma unroll
        for (int k2 = 0; k2 < 25; ++k2) {
            flt2 c = *(const flt2*)(cr + k2*2);
            s += pf[2*k2] * c.x + pf[2*k2+1] * c.y;
        }
        const int r = row0 + (ert >> 1);
        const float u = ((ert & 1) ? gsrc : gtgt)[(size_t)r*CNUM + idx];
        T48l[e] = (s + gnoise(u)) * TAUI;
    }
    __syncthreads();

    // finalize: exact top-8 of 48 (tiebreak lower index) -> global
    if (tid < 16) {
        const int r8 = tid;
        const float inv = 1.0f / (TS[r8*4] + TS[r8*4+1] + TS[r8*4+2] + TS[r8*4+3]);
        u64 used = 0;
        for (int k = 0; k < KSEL; ++k) {
            float bl = -3.4e38f; int bi = 1 << 30; int bj = 0;
            for (int j = 0; j < 48; ++j) {
                if ((used >> j) & 1ull) continue;
                const float lv = T48l[r8*48 + j];
                const int   iv = (int)(T48u[r8*48 + j] & 2047u);
                if (lv > bl || (lv == bl && iv < bi)) { bl = lv; bi = iv; bj = j; }
            }
            used |= 1ull << bj;
            const int grt = blockIdx.x*16 + r8;
            gTW[grt*KSEL + k] = __expf(bl) * inv;
            gTI[grt*KSEL + k] = bi;
        }
    }
}

// =================== epilogue kernel: 16 rows per block =====================
__global__ __launch_bounds__(256, 4)
void mf_epilog(const int* __restrict__ x32,
               const float* __restrict__ suid,
               const float* __restrict__ tiid,
               const float* __restrict__ Cm,
               const float* __restrict__ w2,
               const float* __restrict__ mw1,
               const float* __restrict__ mb1,
               const float* __restrict__ mw2,
               const float* __restrict__ mb2,
               const float* __restrict__ gTW,
               const int*   __restrict__ gTI,
               float* __restrict__ out)
{
    __shared__ int sFlag;
    const int tid = threadIdx.x;
    const int g = tid >> 4, lg = tid & 15;
    const int row = blockIdx.x * 16 + g;

    if (tid == 0) sFlag = 1;
    __syncthreads();
    if (tid < 128) { if (x32[2*tid+1] != 0) atomicAnd(&sFlag, 0); }
    __syncthreads();
    const int is64 = sFlag;

    const int uidx = is64 ? x32[4*row]     : x32[2*row];
    const int iidx = is64 ? x32[4*row + 2] : x32[2*row + 1];

    float uid[10], ti[10];
    #pragma unroll
    for (int d = 0; d < DIMD; ++d) uid[d] = suid[(size_t)uidx*DIMD + d];
    #pragma unroll
    for (int e = 0; e < DIMD; ++e) ti[e] = tiid[(size_t)iidx*DIMD + e];

    float twt[8], tws[8]; int it[8], is_[8];
    #pragma unroll
    for (int k = 0; k < KSEL; ++k) {
        twt[k] = gTW[(row*2)*KSEL + k];     it[k]  = gTI[(row*2)*KSEL + k];
        tws[k] = gTW[(row*2+1)*KSEL + k];   is_[k] = gTI[(row*2+1)*KSEL + k];
    }

    const int j0 = 4*lg;
    const int nj = (j0 + 4 <= MDIM) ? 4 : (j0 < MDIM ? MDIM - j0 : 0);

    float po = 0.f;
    float qt[4] = {0,0,0,0}, w2t[4] = {0,0,0,0}, hb[4] = {0,0,0,0};

    if (nj) {
        {
            flt2 m0 = *(const flt2*)(mb1 + j0);
            hb[0] = m0.x; hb[1] = m0.y;
            if (nj == 4) { flt2 m1 = *(const flt2*)(mb1 + j0 + 2); hb[2] = m1.x; hb[3] = m1.y; }
            #pragma unroll
            for (int d = 0; d < DIMD; ++d) {
                const float* r = mw1 + (MDIM + d)*MDIM + j0;
                flt2 a = *(const flt2*)r;
                hb[0] += uid[d]*a.x; hb[1] += uid[d]*a.y;
                if (nj == 4) { flt2 b = *(const flt2*)(r + 2); hb[2] += uid[d]*b.x; hb[3] += uid[d]*b.y; }
            }
        }
        for (int jj = 0; jj < nj; ++jj) {
            const float* r = w2 + (j0 + jj)*DIMD;
            float s = 0.f;
            #pragma unroll
            for (int p = 0; p < 5; ++p) { flt2 a = *(const flt2*)(r + 2*p); s += a.x*ti[2*p] + a.y*ti[2*p+1]; }
            w2t[jj] = s;
        }
        for (int jj = 0; jj < nj; ++jj) {
            const float* r = mw2 + (size_t)(j0 + jj)*(DIMD*DIMD);
            float s = 0.f;
            #pragma unroll
            for (int d = 0; d < DIMD; ++d) {
                float sd = 0.f;
                #pragma unroll
                for (int p = 0; p < 5; ++p) { flt2 a = *(const flt2*)(r + d*DIMD + 2*p); sd += a.x*ti[2*p] + a.y*ti[2*p+1]; }
                s += uid[d]*sd;
            }
            qt[jj] = s;
        }
        {
            float ws[4] = {0,0,0,0};
            #pragma unroll
            for (int k = 0; k < KSEL; ++k) {
                const float* cr = Cm + (size_t)it[k]*MDIM + j0;
                flt2 a = *(const flt2*)cr;
                ws[0] += twt[k]*a.x; ws[1] += twt[k]*a.y;
                if (nj == 4) { flt2 b = *(const flt2*)(cr + 2); ws[2] += twt[k]*b.x; ws[3] += twt[k]*b.y; }
            }
            for (int jj = 0; jj < nj; ++jj) po += ws[jj]*w2t[jj];
        }
        float hk[8][4];
        #pragma unroll
        for (int k = 0; k < KSEL; ++k)
            #pragma unroll
            for (int jj = 0; jj < 4; ++jj) hk[k][jj] = hb[jj];
        for (int t2 = 0; t2 < MDIM; t2 += 2) {
            const float* r0 = mw1 + t2*MDIM + j0;
            const float* r1 = mw1 + (t2+1)*MDIM + j0;
            flt2 wa0 = *(const flt2*)r0, wb0 = *(const flt2*)(r0 + 2);
            flt2 wa1 = *(const flt2*)r1, wb1 = *(const flt2*)(r1 + 2);
            #pragma unroll
            for (int k = 0; k < KSEL; ++k) {
                flt2 c = *(const flt2*)(Cm + (size_t)is_[k]*MDIM + t2);
                hk[k][0] += c.x*wa0.x + c.y*wa1.x;
                hk[k][1] += c.x*wa0.y + c.y*wa1.y;
                hk[k][2] += c.x*wb0.x + c.y*wb1.x;
                hk[k][3] += c.x*wb0.y + c.y*wb1.y;
            }
        }
        #pragma unroll
        for (int k = 0; k < KSEL; ++k) {
            float s = 0.f;
            for (int jj = 0; jj < nj; ++jj) s += fmaxf(hk[k][jj], 0.f)*qt[jj];
            po += tws[k]*s;
        }
    }
    if (lg == 0) {
        float stw = 0.f;
        #pragma unroll
        for (int k = 0; k < KSEL; ++k) stw += tws[k];
        float bt = 0.f;
        #pragma unroll
        for (int d = 0; d < DIMD; ++d) {
            float sd = 0.f;
            #pragma unroll
            for (int e = 0; e < DIMD; ++e) sd += mb2[d*DIMD + e]*ti[e];
            bt += uid[d]*sd;
        }
        po += stw*bt;
    }
    po += __shfl_xor(po, 1, 16);
    po += __shfl_xor(po, 2, 16);
    po += __shfl_xor(po, 4, 16);
    po += __shfl_xor(po, 8, 16);
    if (lg == 0) out[row] = po;
}

// =================== fused fallback (validated, non-PRE path) ===============
__global__ __launch_bounds__(256, 4)
void mf_fused_fb(const int* __restrict__ x32,
                 const float* __restrict__ gsrc,
                 const float* __restrict__ gtgt,
                 const float* __restrict__ suid,
                 const float* __restrict__ tuid,
                 const float* __restrict__ tiid,
                 const float* __restrict__ Cm,
                 const float* __restrict__ w1,
                 const float* __restrict__ w2,
                 const float* __restrict__ mw1,
                 const float* __restrict__ mb1,
                 const float* __restrict__ mw2,
                 const float* __restrict__ mb2,
                 float* __restrict__ out)
{
    __shared__ __align__(16) float smem[9536];
    __shared__ int sFlag;
    float* sPf  = smem;
    u32*   T24u = (u32*)(smem + 1664);
    float* T24l = smem + 2432;

    const int tid  = threadIdx.x;
    const int row0 = blockIdx.x * 16;

    if (tid == 0) sFlag = 1;
    __syncthreads();
    if (tid < 128) { if (x32[2*tid+1] != 0) atomicAnd(&sFlag, 0); }
    __syncthreads();
    const int is64 = sFlag;

    for (int t = tid; t < 32*52; t += 256) {
        const int rt = t / 52, mm = t - rt*52;
        float v = 0.f;
        if (mm < MDIM) {
            const int r = row0 + (rt >> 1);
            const int uidx = is64 ? x32[4*r] : x32[2*r];
            const float* tab = (rt & 1) ? suid : tuid;
            #pragma unroll
            for (int d = 0; d < DIMD; ++d) v += tab[uidx*DIMD + d] * w1[d*MDIM + mm];
        }
        sPf[t] = v;
    }
    __syncthreads();

    const int lane = tid & 63, wv = tid >> 6;
    const int lr = lane & 15, lk = lane >> 4;
    const int g = wv & 1, h = wv >> 1;
    const int rt = g*16 + lr;
    const float* up = ((lr & 1) ? gsrc : gtgt) + (size_t)(row0 + g*8 + (lr >> 1)) * CNUM;

    half8 b0, b1;
    {
        union { u32 u[4]; half8 v; } c0, c1;
        #pragma unroll
        for (int jj = 0; jj < 4; ++jj) {
            const int k0 = lk*8 + jj*2;
            c0.u[jj] = pkrtz(sPf[rt*52 + k0], sPf[rt*52 + k0 + 1]);
            const int k1 = 32 + lk*8 + jj*2;
            const float e0 = (k1     < 52) ? sPf[rt*52 + k1]     : 0.f;
            const float e1 = (k1 + 1 < 52) ? sPf[rt*52 + k1 + 1] : 0.f;
            c1.u[jj] = pkrtz(e0, e1);
        }
        b0 = c0.v; b1 = c1.v;
    }

    float ts = 0.f;
    float q0=-3.4e38f,q1=-3.4e38f,q2=-3.4e38f,q3=-3.4e38f,
          q4=-3.4e38f,q5=-3.4e38f,q6=-3.4e38f,q7=-3.4e38f;

    for (int t = 0; t < 64; ++t) {
        const int cb = ((t >> 2) << 7) + h*64 + ((t & 3) << 4);
        const float* cr = Cm + (size_t)(cb + lr)*MDIM;
        union { u32 u[4]; half8 v; } c0, c1;
        #pragma unroll
        for (int jj = 0; jj < 4; ++jj) {
            const int k0 = lk*8 + jj*2;
            c0.u[jj] = pkrtz(cr[k0], cr[k0+1]);
            const int k1 = 32 + lk*8 + jj*2;
            const float e0 = (k1     < MDIM) ? cr[k1]   : 0.f;
            const float e1 = (k1 + 1 < MDIM) ? cr[k1+1] : 0.f;
            c1.u[jj] = pkrtz(e0, e1);
        }
        f32x4 acc = {0.f, 0.f, 0.f, 0.f};
        acc = __builtin_amdgcn_mfma_f32_16x16x32_f16(c0.v, b0, acc, 0, 0, 0);
        acc = __builtin_amdgcn_mfma_f32_16x16x32_f16(c1.v, b1, acc, 0, 0, 0);
        const f32x4 u4 = *(const f32x4*)(up + cb + lk*4);
        const int cg = cb + lk*4;
        #pragma unroll
        for (int r4 = 0; r4 < 4; ++r4) {
            const float l = (acc[r4] + gnoise(u4[r4])) * TAUI;
            ts += __expf(l);
            const float xs = __uint_as_float(
                (__float_as_uint(l) & 0xFFFFF800u) | (u32)(cg + r4));
            q0 = fmaxf(q0, fminf(q1, xs));
            q1 = fmaxf(q1, fminf(q2, xs));
            q2 = fmaxf(q2, fminf(q3, xs));
            q3 = fmaxf(q3, fminf(q4, xs));
            q4 = fmaxf(q4, fminf(q5, xs));
            q5 = fmaxf(q5, fminf(q6, xs));
            q6 = fmaxf(q6, fminf(q7, xs));
            q7 = fmaxf(q7, xs);
        }
    }

    {
        float tss = ts;
        tss += __shfl_xor(tss, 16); tss += __shfl_xor(tss, 32);
        if (lk == 0) smem[3200 + rt*2 + h] = tss;
        #pragma unroll
        for (int k = 0; k < 12; ++k) {
            float gm = fmaxf(q7, __shfl_xor(q7, 16));
            gm = fmaxf(gm, __shfl_xor(gm, 32));
            if (q7 == gm) {
                T24u[rt*24 + h*12 + k] = __float_as_uint(q7);
                q7=q6; q6=q5; q5=q4; q4=q3; q3=q2; q2=q1; q1=q0; q0=-3.4e38f;
            }
        }
    }
    __syncthreads();

    for (int e = tid; e < 32*24; e += 256) {
        const int ert = e / 24;
        const int idx = (int)(T24u[e] & 2047u);
        const float* pf = sPf + ert*52;
        const float* cr = Cm + idx*MDIM;
        float s = 0.f;
        #pragma unroll
        for (int k2 = 0; k2 < 25; ++k2) {
            flt2 c = *(const flt2*)(cr + k2*2);
            s += pf[2*k2] * c.x + pf[2*k2+1] * c.y;
        }
        const int r = row0 + (ert >> 1);
        const float u = ((ert & 1) ? gsrc : gtgt)[(size_t)r*CNUM + idx];
        T24l[e] = (s + gnoise(u)) * TAUI;
    }
    __syncthreads();

    if (tid < 32) {
        const int rrt = tid;
        const float inv = 1.0f / (smem[3200 + rrt*2] + smem[3200 + rrt*2 + 1]);
        u32 used = 0;
        for (int k = 0; k < KSEL; ++k) {
            float bl = -3.4e38f; int bi = 1 << 30; int bj = 0;
            for (int j = 0; j < 24; ++j) {
                if ((used >> j) & 1) continue;
                const float lv = T24l[rrt*24 + j];
                const int   iv = (int)(T24u[rrt*24 + j] & 2047u);
                if (lv > bl || (lv == bl && iv < bi)) { bl = lv; bi = iv; bj = j; }
            }
            used |= 1u << bj;
            smem[8832 + rrt*KSEL + k] = __expf(bl) * inv;
            ((int*)smem)[9088 + rrt*KSEL + k] = bi;
        }
    }
    __syncthreads();

    float* sH    = smem;
    float* sQ    = smem + 832;
    float* sUd   = smem + 9344;
    float* sTopW = smem + 8832;
    int*   sTopI = (int*)smem + 9088;

    const int gg = tid >> 4, lg = tid & 15;
    const int row = row0 + gg;
    const int rt_t = gg*2, rt_s = gg*2 + 1;
    const int uidx = is64 ? x32[4*row]     : x32[2*row];
    const int iidx = is64 ? x32[4*row + 2] : x32[2*row + 1];

    if (lg < DIMD) sUd[gg*12 + lg] = suid[uidx*DIMD + lg];
    __syncthreads();

    for (int t = lg; t < MDIM*DIMD; t += 16) {
        const int j = t / DIMD, e = t - j*DIMD;
        float q = 0.f;
        #pragma unroll
        for (int d = 0; d < DIMD; ++d) q += sUd[gg*12 + d] * mw2[j*(DIMD*DIMD) + d*DIMD + e];
        sQ[gg*500 + t] = q;
    }
    for (int mm = lg; mm < MDIM; mm += 16) {
        float v = 0.f;
        #pragma unroll
        for (int k = 0; k < KSEL; ++k)
            v += sTopW[rt_t*KSEL + k] * Cm[sTopI[rt_t*KSEL + k]*MDIM + mm];
        sH[gg*52 + mm] = v;
    }
    __syncthreads();

    float acc_e = 0.f, be = 0.f;
    if (lg < DIMD) {
        for (int m2 = 0; m2 < MDIM; ++m2) acc_e += sH[gg*52 + m2] * w2[m2*DIMD + lg];
        #pragma unroll
        for (int d = 0; d < DIMD; ++d) be += sUd[gg*12 + d] * mb2[d*DIMD + lg];
    }
    __syncthreads();

    for (int k = 0; k < KSEL; ++k) {
        const int   ik = sTopI[rt_s*KSEL + k];
        const float tw = sTopW[rt_s*KSEL + k];
        for (int j = lg; j < MDIM; j += 16) {
            float hh = mb1[j];
            const float* crow = Cm + ik*MDIM;
            for (int t2 = 0; t2 < MDIM; ++t2) hh += crow[t2] * mw1[t2*MDIM + j];
            #pragma unroll
            for (int d = 0; d < DIMD; ++d) hh += sUd[gg*12 + d] * mw1[(MDIM + d)*MDIM + j];
            sH[gg*52 + j] = fmaxf(hh, 0.f);
        }
        __syncthreads();
        if (lg < DIMD) {
            float se = be;
            for (int j = 0; j < MDIM; ++j) se += sH[gg*52 + j] * sQ[gg*500 + j*DIMD + lg];
            acc_e += tw * se;
        }
        __syncthreads();
    }

    float o = 0.f;
    if (lg < DIMD) o = acc_e * tiid[iidx*DIMD + lg];
    #pragma unroll
    for (int k = 8; k >= 1; k >>= 1) o += __shfl_xor(o, k, 16);
    if (lg == 0) out[row] = o;
}

extern "C" void kernel_launch(void* const* d_in, const int* in_sizes, int n_in,
                              void* d_out, int out_size, void* d_ws, size_t ws_size,
                              hipStream_t stream) {
    (void)in_sizes; (void)n_in; (void)out_size;
    const int*   x32  = (const int*)d_in[0];
    const float* gsrc = (const float*)d_in[1];
    const float* gtgt = (const float*)d_in[2];
    const float* suid = (const float*)d_in[3];
    const float* tuid = (const float*)d_in[4];
    const float* tiid = (const float*)d_in[5];
    const float* Cm   = (const float*)d_in[6];
    const float* w1   = (const float*)d_in[7];
    const float* w2   = (const float*)d_in[8];
    const float* mw1  = (const float*)d_in[9];
    const float* mb1  = (const float*)d_in[10];
    const float* mw2  = (const float*)d_in[11];
    const float* mb2  = (const float*)d_in[12];

    // ws layout (words): C16 [0,131072) ; gTW [131072,393216) ; gTI [393216,655360)
    if (ws_size >= 655360u * 4u) {
        u32*   C16 = (u32*)d_ws;
        float* gTW = (float*)d_ws + 131072;
        int*   gTI = (int*)d_ws + 393216;
        hipLaunchKernelGGL(cvtC, dim3(512), dim3(256), 0, stream, Cm, C16);
        hipLaunchKernelGGL(mf_route, dim3(BROWS/8), dim3(256), 0, stream,
                           x32, gsrc, gtgt, suid, tuid, Cm, w1, C16, gTW, gTI);
        hipLaunchKernelGGL(mf_epilog, dim3(BROWS/16), dim3(256), 0, stream,
                           x32, suid, tiid, Cm, w2, mw1, mb1, mw2, mb2, gTW, gTI,
                           (float*)d_out);
    } else {
        hipLaunchKernelGGL(mf_fused_fb, dim3(BROWS/16), dim3(256), 0, stream,
                           x32, gsrc, gtgt, suid, tuid, tiid, Cm, w1, w2, mw1, mb1, mw2, mb2,
                           (float*)d_out);
    }
}